// Round 9
// baseline (146.942 us; speedup 1.0000x reference)
//
#include <hip/hip_runtime.h>

// MHA forward, MI355X gfx950.
// R9: attn_fwd rewritten with NO LDS, NO barriers — K/V fragments loaded
//     global->VGPR directly (L2/L3-resident), register double-buffer, counted
//     vmcnt(16) prefetch. 4 independent waves per block. GEMMs unchanged (R6).

#define SEQ   2048
#define DMODEL 1024
#define NH    16
#define HD    64
#define MROWS 4096   // b*t = 2*2048

typedef __attribute__((ext_vector_type(4))) float f32x4;
typedef __attribute__((ext_vector_type(16))) float f32x16;
typedef __attribute__((ext_vector_type(8))) short short8;
typedef __attribute__((ext_vector_type(4))) unsigned int u32x4;

#define MFMA16(a, b, c) __builtin_amdgcn_mfma_f32_16x16x32_bf16((a), (b), (c), 0, 0, 0)
#define MFMA32(a, b, c) __builtin_amdgcn_mfma_f32_32x32x16_bf16((a), (b), (c), 0, 0, 0)

__device__ __forceinline__ unsigned short f2bf(float f) {
  union { float f; unsigned u; } v; v.f = f;
  return (unsigned short)((v.u + 0x7fffu + ((v.u >> 16) & 1u)) >> 16);
}

__device__ __forceinline__ float exp2x(float x) {
#if __has_builtin(__builtin_amdgcn_exp2f)
  return __builtin_amdgcn_exp2f(x);
#else
  float r; asm("v_exp_f32 %0, %1" : "=v"(r) : "v"(x)); return r;
#endif
}

__device__ __forceinline__ unsigned cvt_pk(float lo, float hi) {
  unsigned r;
  asm volatile("v_cvt_pk_bf16_f32 %0, %1, %2" : "=v"(r) : "v"(lo), "v"(hi));
  return r;
}

// v_permlane32_swap: a' = [a.lo | b.lo-in-hi-lanes], b' = [a.hi-in-lo-lanes | b.hi]
__device__ __forceinline__ void pls(unsigned& a, unsigned& b) {
  asm("v_permlane32_swap_b32 %0, %1" : "+v"(a), "+v"(b));
}

__device__ __forceinline__ short8 as_short8(u32x4 v) {
  union { u32x4 u; short8 s; } x; x.u = v; return x.s;
}

__device__ __forceinline__ f32x4 zero4() {
  f32x4 z; z[0] = 0.f; z[1] = 0.f; z[2] = 0.f; z[3] = 0.f; return z;
}

// async global->LDS, 16B per lane, linear dest (wave base + lane*16)
__device__ __forceinline__ void async16(const void* g, void* l) {
  __builtin_amdgcn_global_load_lds(
      (const __attribute__((address_space(1))) unsigned int*)g,
      (__attribute__((address_space(3))) unsigned int*)l, 16, 0, 0);
}

// ---------------- x -> bf16 ----------------
__global__ __launch_bounds__(256) void xconv(const float* __restrict__ x,
                                             unsigned short* __restrict__ xb) {
  int i = blockIdx.x * 256 + threadIdx.x;      // handles 8 elements
  const float4* p = (const float4*)x;
  float4 a = p[2 * i];
  float4 b = p[2 * i + 1];
  short8 o;
  o[0] = (short)f2bf(a.x); o[1] = (short)f2bf(a.y);
  o[2] = (short)f2bf(a.z); o[3] = (short)f2bf(a.w);
  o[4] = (short)f2bf(b.x); o[5] = (short)f2bf(b.y);
  o[6] = (short)f2bf(b.z); o[7] = (short)f2bf(b.w);
  *(short8*)&xb[(size_t)i * 8] = o;
}

// ---------------- W[k][n] fp32 -> Wt[n][k] bf16 (64x64 tiles via LDS) ----------------
__global__ __launch_bounds__(256) void wtrans(const float* __restrict__ W,
                                              unsigned short* __restrict__ Wt) {
  __shared__ unsigned short tile[64][65];
  int t = threadIdx.x;
  int tx = t & 63, ty = t >> 6;               // ty 0..3
  int kb = blockIdx.x * 64, nb = blockIdx.y * 64;
#pragma unroll
  for (int rr = 0; rr < 16; rr++) {
    int r = ty * 16 + rr;
    tile[r][tx] = f2bf(W[(size_t)(kb + r) * 1024 + nb + tx]);
  }
  __syncthreads();
#pragma unroll
  for (int rr = 0; rr < 16; rr++) {
    int r = ty * 16 + rr;
    Wt[(size_t)(nb + r) * 1024 + kb + tx] = tile[tx][r];
  }
}

// ---------------- V[b,h,t,d] bf16 -> Vt[b,h,d,t] bf16 ----------------
__global__ __launch_bounds__(256) void vtrans(const unsigned short* __restrict__ V,
                                              unsigned short* __restrict__ Vt) {
  __shared__ unsigned short tile[64][65];
  int t = threadIdx.x;
  int tx = t & 63, ty = t >> 6;               // ty 0..3
  int bh = blockIdx.x, t0 = blockIdx.y * 64;
  const unsigned short* src = V + ((size_t)bh * SEQ + t0) * HD;
  unsigned short* dst = Vt + (size_t)bh * HD * SEQ + t0;
#pragma unroll
  for (int rr = 0; rr < 16; rr++) {
    int r = ty * 16 + rr;                      // t-offset
    tile[r][tx] = src[(size_t)r * HD + tx];
  }
  __syncthreads();
#pragma unroll
  for (int rr = 0; rr < 16; rr++) {
    int r = ty * 16 + rr;                      // d-index
    dst[(size_t)r * SEQ + tx] = tile[tx][r];
  }
}

// ---------------- GEMM: C[M,N] = A[M,1024] * Bt[N,1024]^T ----------------
// (unchanged from R6: 3-buffer 2-deep pipeline, chunk-XOR LDS swizzle, XCD swizzle)
template <int MODE, int WMF>
__global__ __launch_bounds__(256) void gemm_bt(
    const unsigned short* __restrict__ A, const unsigned short* __restrict__ Bt,
    unsigned short* __restrict__ Qo, unsigned short* __restrict__ Ko,
    unsigned short* __restrict__ Vo, float* __restrict__ out,
    const float* __restrict__ bo) {
  constexpr int K = 1024;
  constexpr int BM = WMF * 32;
  constexpr int NT = K / 32;                    // 32 k-tiles
  __shared__ __align__(16) unsigned short As[3][BM * 32];
  __shared__ __align__(16) unsigned short Bs[3][128 * 32];
  const int t = threadIdx.x;
  const int lane = t & 63;
  const int w = t >> 6;
  const int lr = lane & 15, kf = lane >> 4;
  const int wr = w >> 1, wc = w & 1;

  // XCD-aware swizzle (8 XCDs; nwg multiple of 8)
  const int nwg = gridDim.x * gridDim.y;
  const int id = blockIdx.y * gridDim.x + blockIdx.x;
  const int swz = (id & 7) * (nwg >> 3) + (id >> 3);
  const int bx = swz % gridDim.x, by = swz / gridDim.x;

  const int rowbase = bx * BM;
  const int colbase = by * 128;

  const unsigned short* Ab = A + (size_t)rowbase * K;
  const unsigned short* Bb = Bt + (size_t)colbase * K;

  f32x4 acc[WMF][4];
#pragma unroll
  for (int m = 0; m < WMF; m++)
#pragma unroll
    for (int n = 0; n < 4; n++) acc[m][n] = zero4();

  // physical 16B chunk f takes global data of logical chunk c = f ^ ((f>>3)&3)
  auto stage = [&](int buf, int kt) {
    int k0 = kt * 32;
#pragma unroll
    for (int i = 0; i < BM / 64; i++) {
      int f = i * 256 + t;          // A physical chunk id
      int c = f ^ ((f >> 3) & 3);
      int row = c >> 2;             // 4 chunks per 32-elem row
      int col = (c & 3) << 3;
      async16(Ab + (size_t)row * K + k0 + col, (char*)&As[buf][0] + (size_t)f * 16);
    }
#pragma unroll
    for (int i = 0; i < 2; i++) {
      int f = i * 256 + t;          // B physical chunk id, 0..511
      int c = f ^ ((f >> 3) & 3);
      int row = c >> 2;
      int col = (c & 3) << 3;
      async16(Bb + (size_t)row * K + k0 + col, (char*)&Bs[buf][0] + (size_t)f * 16);
    }
  };

  stage(0, 0);
  stage(1, 1);

  for (int kt = 0; kt < NT; kt++) {
    if (kt + 2 < NT) {
      stage((kt + 2) % 3, kt + 2);  // two stages in flight beyond current
      if constexpr (MODE == 0) asm volatile("s_waitcnt vmcnt(8)" ::: "memory");
      else                     asm volatile("s_waitcnt vmcnt(6)" ::: "memory");
    } else if (kt + 1 < NT) {
      if constexpr (MODE == 0) asm volatile("s_waitcnt vmcnt(4)" ::: "memory");
      else                     asm volatile("s_waitcnt vmcnt(3)" ::: "memory");
    } else {
      asm volatile("s_waitcnt vmcnt(0)" ::: "memory");
    }
    __builtin_amdgcn_s_barrier();   // all waves' current-tile loads landed

    const int cur = kt % 3;
    short8 av[WMF], bv[4];
#pragma unroll
    for (int m = 0; m < WMF; m++) {
      int row = wr * (WMF * 16) + m * 16 + lr;
      int idx = (row * 32 + kf * 8) ^ (((row >> 1) & 3) << 3);
      av[m] = *(const short8*)&As[cur][idx];
    }
#pragma unroll
    for (int n = 0; n < 4; n++) {
      int row = wc * 64 + n * 16 + lr;
      int idx = (row * 32 + kf * 8) ^ (((row >> 1) & 3) << 3);
      bv[n] = *(const short8*)&Bs[cur][idx];
    }
    __builtin_amdgcn_s_setprio(1);
#pragma unroll
    for (int m = 0; m < WMF; m++)
#pragma unroll
      for (int n = 0; n < 4; n++) acc[m][n] = MFMA16(av[m], bv[n], acc[m][n]);
    __builtin_amdgcn_s_setprio(0);
    __builtin_amdgcn_s_barrier();   // reads of cur done before it gets restaged
  }

  // Epilogue. C/D layout: col = lane&15, row = (lane>>4)*4 + i  [m89-verified]
  if constexpr (MODE == 0) {
#pragma unroll
    for (int n = 0; n < 4; n++) {
      int c = colbase + wc * 64 + n * 16 + lr;   // 0..3071
      int sel = c >> 10;                          // 0=Q 1=K 2=V (uniform per n)
      int hh = (c >> 6) & 15;
      int dd = c & 63;
      unsigned short* dst = (sel == 0) ? Qo : ((sel == 1) ? Ko : Vo);
      // fold softmax scale (1/8) and log2(e) into Q so attn uses exp2 directly
      const float sc = (sel == 0) ? 0.18033688011112042f : 1.0f;
#pragma unroll
      for (int m = 0; m < WMF; m++) {
        int r0 = rowbase + wr * (WMF * 16) + m * 16 + kf * 4;
#pragma unroll
        for (int i = 0; i < 4; i++) {
          int r = r0 + i;
          int bi = r >> 11;         // batch
          int tq = r & 2047;        // token
          size_t off = ((size_t)(bi * NH + hh) * SEQ + tq) * HD + dd;  // uniform, coalesced
          dst[off] = f2bf(acc[m][n][i] * sc);
        }
      }
    }
  } else {
#pragma unroll
    for (int n = 0; n < 4; n++) {
      int c = colbase + wc * 64 + n * 16 + lr;
      float bias = bo[c];
#pragma unroll
      for (int m = 0; m < WMF; m++) {
        int r0 = rowbase + wr * (WMF * 16) + m * 16 + kf * 4;
#pragma unroll
        for (int i = 0; i < 4; i++) {
          out[(size_t)(r0 + i) * 1024 + c] = acc[m][n][i] + bias;
        }
      }
    }
  }
}

// ---------------- flash attention (no-LDS, register double-buffer) ----------------
// grid: x = b*H (32), y = 16 -> qt via pair-balanced remap. 256 thr, 4 waves,
// fully independent (no barriers, no LDS). Wave w: q rows [qt*128+w*32, +32).
// K/V frags loaded global->VGPR (L2-resident); prefetch next tile into the
// alternate register set; s_waitcnt vmcnt(16) keeps 16 loads in flight.
__global__ __launch_bounds__(256, 2) void attn_fwd(
    const unsigned short* __restrict__ Q, const unsigned short* __restrict__ K,
    const unsigned short* __restrict__ Vt, unsigned short* __restrict__ ctx) {
  const int bh = blockIdx.x;
  const int y = blockIdx.y;
  const int qt = (y < 8) ? (15 - y) : (y - 8);   // co-resident pairs sum ~constant
  const int bi = bh >> 4, hh = bh & 15;
  const int t = threadIdx.x, lane = t & 63, w = t >> 6;
  const int qc = lane & 31, hi = lane >> 5;

  const unsigned short* Qb = Q + (size_t)bh * SEQ * HD;
  const unsigned short* Kb = K + (size_t)bh * SEQ * HD;
  const unsigned short* Vb = Vt + (size_t)bh * HD * SEQ;

  const int qrow = qt * 128 + w * 32;
  short8 qv[4];
#pragma unroll
  for (int c = 0; c < 4; c++)
    qv[c] = *(const short8*)&Qb[(size_t)(qrow + qc) * HD + c * 16 + hi * 8];

  f32x16 o0, o1;                    // O^T[d][q]: o0 = d 0..31, o1 = 32..63
#pragma unroll
  for (int i = 0; i < 16; i++) { o0[i] = 0.f; o1[i] = 0.f; }
  float l_acc = 0.f;

  const int ktmax = 2 * qt + (w >> 1);   // this wave's diagonal tile

  short8 kA[8], vA[8], kB[8], vB[8];

  auto loadKV = [&](short8* kf, short8* vf, int kt) {
    const unsigned short* Kt = Kb + (size_t)kt * 64 * HD;   // [64 k][64 d]
    const unsigned short* Vp = Vb + (size_t)kt * 64;        // [64 d][SEQ] col kt*64
#pragma unroll
    for (int c = 0; c < 4; c++) {
      kf[c]     = *(const short8*)&Kt[qc * 64 + c * 16 + hi * 8];
      kf[4 + c] = *(const short8*)&Kt[(32 + qc) * 64 + c * 16 + hi * 8];
      vf[c]     = *(const short8*)&Vp[(size_t)qc * SEQ + c * 16 + hi * 8];
      vf[4 + c] = *(const short8*)&Vp[(size_t)(32 + qc) * SEQ + c * 16 + hi * 8];
    }
  };

  // one 64-k tile from register fragments: QK^T -> (mask) -> exp2 -> pack -> PV
  auto tilec = [&](const short8* kf, const short8* vf, int kt) {
    f32x16 s0, s1;
#pragma unroll
    for (int i = 0; i < 16; i++) { s0[i] = 0.f; s1[i] = 0.f; }
    __builtin_amdgcn_s_setprio(1);
#pragma unroll
    for (int c = 0; c < 4; c++) {
      s0 = MFMA32(kf[c], qv[c], s0);
      s1 = MFMA32(kf[4 + c], qv[c], s1);
    }
    __builtin_amdgcn_s_setprio(0);

    if (kt == ktmax) {               // causal mask, diagonal tile only
      const int qg = qrow + qc;
#pragma unroll
      for (int reg = 0; reg < 16; reg++) {
        int rloc = (reg & 3) + 8 * (reg >> 2) + 4 * hi;
        int kg = kt * 64 + rloc;
        if (kg > qg) s0[reg] = -1e30f;
        if (kg + 32 > qg) s1[reg] = -1e30f;
      }
    }

    unsigned w0[8], w1[8];
    float psA = 0.f, psB = 0.f;
#pragma unroll
    for (int j = 0; j < 8; j++) {
      float a0 = exp2x(s0[2 * j]), b0 = exp2x(s0[2 * j + 1]);
      float a1 = exp2x(s1[2 * j]), b1 = exp2x(s1[2 * j + 1]);
      psA += a0 + b0;
      psB += a1 + b1;
      w0[j] = cvt_pk(a0, b0);
      w1[j] = cvt_pk(a1, b1);
    }
    l_acc += psA + psB;

    __builtin_amdgcn_s_setprio(1);
#pragma unroll
    for (int h2 = 0; h2 < 2; h2++) {
      unsigned* pw = h2 ? w1 : w0;
#pragma unroll
      for (int cc = 0; cc < 2; cc++) {
        unsigned a0 = pw[cc * 4 + 0], b0 = pw[cc * 4 + 2];
        unsigned a1 = pw[cc * 4 + 1], b1 = pw[cc * 4 + 3];
        pls(a0, b0);                 // (pf0,pf2) both halves in one instr
        pls(a1, b1);                 // (pf1,pf3)
        u32x4 pf; pf[0] = a0; pf[1] = a1; pf[2] = b0; pf[3] = b1;
        short8 pfrag = as_short8(pf);
        int c2 = h2 * 2 + cc;
        o0 = MFMA32(vf[c2], pfrag, o0);
        o1 = MFMA32(vf[4 + c2], pfrag, o1);
      }
    }
    __builtin_amdgcn_s_setprio(0);
  };

  loadKV(kA, vA, 0);

  int kt = 0;
  for (;;) {
    // even tile: compute A, prefetch into B
    if (kt + 1 <= ktmax) {
      loadKV(kB, vB, kt + 1);
      asm volatile("s_waitcnt vmcnt(16)" ::: "memory");   // A landed; B in flight
    } else {
      asm volatile("s_waitcnt vmcnt(0)" ::: "memory");
    }
    tilec(kA, vA, kt);
    if (++kt > ktmax) break;

    // odd tile: compute B, prefetch into A
    if (kt + 1 <= ktmax) {
      loadKV(kA, vA, kt + 1);
      asm volatile("s_waitcnt vmcnt(16)" ::: "memory");
    } else {
      asm volatile("s_waitcnt vmcnt(0)" ::: "memory");
    }
    tilec(kB, vB, kt);
    if (++kt > ktmax) break;
  }

  // epilogue: l = in-lane sum + one cross-half swap; O/l -> ctx
  float l = l_acc + __shfl_xor(l_acc, 32);
  float inv = 1.0f / l;
  const size_t rowoff = ((size_t)bi * SEQ + qrow + qc) * DMODEL + hh * HD;
#pragma unroll
  for (int g = 0; g < 4; g++) {
    unsigned pa = cvt_pk(o0[4 * g] * inv, o0[4 * g + 1] * inv);
    unsigned pb = cvt_pk(o0[4 * g + 2] * inv, o0[4 * g + 3] * inv);
    uint2 vv; vv.x = pa; vv.y = pb;
    *(uint2*)&ctx[rowoff + 8 * g + 4 * hi] = vv;
    unsigned pc = cvt_pk(o1[4 * g] * inv, o1[4 * g + 1] * inv);
    unsigned pd = cvt_pk(o1[4 * g + 2] * inv, o1[4 * g + 3] * inv);
    uint2 ww; ww.x = pc; ww.y = pd;
    *(uint2*)&ctx[rowoff + 32 + 8 * g + 4 * hi] = ww;
  }
}

// ---------------- launch ----------------
extern "C" void kernel_launch(void* const* d_in, const int* in_sizes, int n_in,
                              void* d_out, int out_size, void* d_ws, size_t ws_size,
                              hipStream_t stream) {
  const float* x  = (const float*)d_in[0];
  const float* Wq = (const float*)d_in[1];
  const float* Wk = (const float*)d_in[2];
  const float* Wv = (const float*)d_in[3];
  const float* Wo = (const float*)d_in[4];
  const float* bo = (const float*)d_in[5];
  float* out = (float*)d_out;

  unsigned short* xb   = (unsigned short*)d_ws;                 // 4M elems
  unsigned short* Wt   = xb + (size_t)MROWS * DMODEL;           // 3M (Wq^T|Wk^T|Wv^T)
  unsigned short* WoT  = Wt + (size_t)3 * 1024 * 1024;          // 1M
  unsigned short* Qb   = WoT + (size_t)1024 * 1024;             // 4M
  unsigned short* Kb   = Qb + (size_t)MROWS * DMODEL;           // 4M
  unsigned short* Vb   = Kb + (size_t)MROWS * DMODEL;           // 4M  V^T [b,h,d,t]
  unsigned short* ctxb = Vb + (size_t)MROWS * DMODEL;           // 4M  (aliased: V normal pre-vtrans, ctx post-attn)

  xconv<<<2048, 256, 0, stream>>>(x, xb);
  dim3 tg(16, 16);
  wtrans<<<tg, 256, 0, stream>>>(Wq, Wt);
  wtrans<<<tg, 256, 0, stream>>>(Wk, Wt + (size_t)1024 * 1024);
  wtrans<<<tg, 256, 0, stream>>>(Wv, Wt + (size_t)2 * 1024 * 1024);
  wtrans<<<tg, 256, 0, stream>>>(Wo, WoT);

  // V written un-transposed into ctxb slot, then transposed into Vb
  gemm_bt<0, 4><<<dim3(32, 24), 256, 0, stream>>>(xb, Wt, Qb, Kb, ctxb, nullptr, nullptr);
  vtrans<<<dim3(32, 32), 256, 0, stream>>>(ctxb, Vb);
  attn_fwd<<<dim3(32, 16), 256, 0, stream>>>(Qb, Kb, Vb, ctxb);
  gemm_bt<1, 2><<<dim3(64, 8), 256, 0, stream>>>(ctxb, WoT, nullptr, nullptr, nullptr, out, bo);
}

// Round 10
// 120.820 us; speedup vs baseline: 1.2162x; 1.2162x over previous
//
#include <hip/hip_runtime.h>

// MHA forward, MI355X gfx950.
// R10: attn back to the R6-proven 4-wave math but single-tile dbuf (32KB LDS ->
//      5 blocks/CU vs 2) + heavy-first dispatch. xconv+wtrans merged into one
//      prep kernel (9 -> 5 launches). GEMMs unchanged from R6.

#define SEQ   2048
#define DMODEL 1024
#define NH    16
#define HD    64
#define MROWS 4096   // b*t = 2*2048

typedef __attribute__((ext_vector_type(4))) float f32x4;
typedef __attribute__((ext_vector_type(16))) float f32x16;
typedef __attribute__((ext_vector_type(8))) short short8;
typedef __attribute__((ext_vector_type(4))) unsigned int u32x4;

#define MFMA16(a, b, c) __builtin_amdgcn_mfma_f32_16x16x32_bf16((a), (b), (c), 0, 0, 0)
#define MFMA32(a, b, c) __builtin_amdgcn_mfma_f32_32x32x16_bf16((a), (b), (c), 0, 0, 0)

__device__ __forceinline__ unsigned short f2bf(float f) {
  union { float f; unsigned u; } v; v.f = f;
  return (unsigned short)((v.u + 0x7fffu + ((v.u >> 16) & 1u)) >> 16);
}

__device__ __forceinline__ float exp2x(float x) {
#if __has_builtin(__builtin_amdgcn_exp2f)
  return __builtin_amdgcn_exp2f(x);
#else
  float r; asm("v_exp_f32 %0, %1" : "=v"(r) : "v"(x)); return r;
#endif
}

__device__ __forceinline__ unsigned cvt_pk(float lo, float hi) {
  unsigned r;
  asm volatile("v_cvt_pk_bf16_f32 %0, %1, %2" : "=v"(r) : "v"(lo), "v"(hi));
  return r;
}

// v_permlane32_swap: a' = [a.lo | b.lo-in-hi-lanes], b' = [a.hi-in-lo-lanes | b.hi]
__device__ __forceinline__ void pls(unsigned& a, unsigned& b) {
  asm("v_permlane32_swap_b32 %0, %1" : "+v"(a), "+v"(b));
}

__device__ __forceinline__ short8 as_short8(u32x4 v) {
  union { u32x4 u; short8 s; } x; x.u = v; return x.s;
}

__device__ __forceinline__ f32x4 zero4() {
  f32x4 z; z[0] = 0.f; z[1] = 0.f; z[2] = 0.f; z[3] = 0.f; return z;
}

// async global->LDS, 16B per lane, linear dest (wave base + lane*16)
__device__ __forceinline__ void async16(const void* g, void* l) {
  __builtin_amdgcn_global_load_lds(
      (const __attribute__((address_space(1))) unsigned int*)g,
      (__attribute__((address_space(3))) unsigned int*)l, 16, 0, 0);
}

// ---------------- prep: x->bf16 (blocks 0..2047) + 4x W transpose (2048..3071) ----------------
__global__ __launch_bounds__(256) void prep(
    const float* __restrict__ x, const float* __restrict__ Wq,
    const float* __restrict__ Wk, const float* __restrict__ Wv,
    const float* __restrict__ Wo, unsigned short* __restrict__ xb,
    unsigned short* __restrict__ Wt, unsigned short* __restrict__ WoT) {
  __shared__ unsigned short tile[64][65];
  const int bx = blockIdx.x;
  if (bx < 2048) {
    int i = bx * 256 + threadIdx.x;            // handles 8 elements
    const float4* p = (const float4*)x;
    float4 a = p[2 * i];
    float4 b = p[2 * i + 1];
    short8 o;
    o[0] = (short)f2bf(a.x); o[1] = (short)f2bf(a.y);
    o[2] = (short)f2bf(a.z); o[3] = (short)f2bf(a.w);
    o[4] = (short)f2bf(b.x); o[5] = (short)f2bf(b.y);
    o[6] = (short)f2bf(b.z); o[7] = (short)f2bf(b.w);
    *(short8*)&xb[(size_t)i * 8] = o;
    return;
  }
  const int id2 = bx - 2048;
  const int m = id2 >> 8;                      // which matrix
  const float* W = (m == 0) ? Wq : (m == 1) ? Wk : (m == 2) ? Wv : Wo;
  unsigned short* D = (m == 3) ? WoT : Wt + (size_t)m * 1024 * 1024;
  const int tid = id2 & 255;
  const int kb = (tid >> 4) * 64, nb = (tid & 15) * 64;
  const int t = threadIdx.x;
  const int tx = t & 63, ty = t >> 6;          // ty 0..3
#pragma unroll
  for (int rr = 0; rr < 16; rr++) {
    int r = ty * 16 + rr;
    tile[r][tx] = f2bf(W[(size_t)(kb + r) * 1024 + nb + tx]);
  }
  __syncthreads();
#pragma unroll
  for (int rr = 0; rr < 16; rr++) {
    int r = ty * 16 + rr;
    D[(size_t)(nb + r) * 1024 + kb + tx] = tile[tx][r];
  }
}

// ---------------- V[b,h,t,d] bf16 -> Vt[b,h,d,t] bf16 ----------------
__global__ __launch_bounds__(256) void vtrans(const unsigned short* __restrict__ V,
                                              unsigned short* __restrict__ Vt) {
  __shared__ unsigned short tile[64][65];
  int t = threadIdx.x;
  int tx = t & 63, ty = t >> 6;               // ty 0..3
  int bh = blockIdx.x, t0 = blockIdx.y * 64;
  const unsigned short* src = V + ((size_t)bh * SEQ + t0) * HD;
  unsigned short* dst = Vt + (size_t)bh * HD * SEQ + t0;
#pragma unroll
  for (int rr = 0; rr < 16; rr++) {
    int r = ty * 16 + rr;                      // t-offset
    tile[r][tx] = src[(size_t)r * HD + tx];
  }
  __syncthreads();
#pragma unroll
  for (int rr = 0; rr < 16; rr++) {
    int r = ty * 16 + rr;                      // d-index
    dst[(size_t)r * SEQ + tx] = tile[tx][r];
  }
}

// ---------------- GEMM: C[M,N] = A[M,1024] * Bt[N,1024]^T ----------------
// (unchanged from R6: 3-buffer 2-deep pipeline, chunk-XOR LDS swizzle, XCD swizzle)
template <int MODE, int WMF>
__global__ __launch_bounds__(256) void gemm_bt(
    const unsigned short* __restrict__ A, const unsigned short* __restrict__ Bt,
    unsigned short* __restrict__ Qo, unsigned short* __restrict__ Ko,
    unsigned short* __restrict__ Vo, float* __restrict__ out,
    const float* __restrict__ bo) {
  constexpr int K = 1024;
  constexpr int BM = WMF * 32;
  constexpr int NT = K / 32;                    // 32 k-tiles
  __shared__ __align__(16) unsigned short As[3][BM * 32];
  __shared__ __align__(16) unsigned short Bs[3][128 * 32];
  const int t = threadIdx.x;
  const int lane = t & 63;
  const int w = t >> 6;
  const int lr = lane & 15, kf = lane >> 4;
  const int wr = w >> 1, wc = w & 1;

  // XCD-aware swizzle (8 XCDs; nwg multiple of 8)
  const int nwg = gridDim.x * gridDim.y;
  const int id = blockIdx.y * gridDim.x + blockIdx.x;
  const int swz = (id & 7) * (nwg >> 3) + (id >> 3);
  const int bx = swz % gridDim.x, by = swz / gridDim.x;

  const int rowbase = bx * BM;
  const int colbase = by * 128;

  const unsigned short* Ab = A + (size_t)rowbase * K;
  const unsigned short* Bb = Bt + (size_t)colbase * K;

  f32x4 acc[WMF][4];
#pragma unroll
  for (int m = 0; m < WMF; m++)
#pragma unroll
    for (int n = 0; n < 4; n++) acc[m][n] = zero4();

  // physical 16B chunk f takes global data of logical chunk c = f ^ ((f>>3)&3)
  auto stage = [&](int buf, int kt) {
    int k0 = kt * 32;
#pragma unroll
    for (int i = 0; i < BM / 64; i++) {
      int f = i * 256 + t;          // A physical chunk id
      int c = f ^ ((f >> 3) & 3);
      int row = c >> 2;             // 4 chunks per 32-elem row
      int col = (c & 3) << 3;
      async16(Ab + (size_t)row * K + k0 + col, (char*)&As[buf][0] + (size_t)f * 16);
    }
#pragma unroll
    for (int i = 0; i < 2; i++) {
      int f = i * 256 + t;          // B physical chunk id, 0..511
      int c = f ^ ((f >> 3) & 3);
      int row = c >> 2;
      int col = (c & 3) << 3;
      async16(Bb + (size_t)row * K + k0 + col, (char*)&Bs[buf][0] + (size_t)f * 16);
    }
  };

  stage(0, 0);
  stage(1, 1);

  for (int kt = 0; kt < NT; kt++) {
    if (kt + 2 < NT) {
      stage((kt + 2) % 3, kt + 2);  // two stages in flight beyond current
      if constexpr (MODE == 0) asm volatile("s_waitcnt vmcnt(8)" ::: "memory");
      else                     asm volatile("s_waitcnt vmcnt(6)" ::: "memory");
    } else if (kt + 1 < NT) {
      if constexpr (MODE == 0) asm volatile("s_waitcnt vmcnt(4)" ::: "memory");
      else                     asm volatile("s_waitcnt vmcnt(3)" ::: "memory");
    } else {
      asm volatile("s_waitcnt vmcnt(0)" ::: "memory");
    }
    __builtin_amdgcn_s_barrier();   // all waves' current-tile loads landed

    const int cur = kt % 3;
    short8 av[WMF], bv[4];
#pragma unroll
    for (int m = 0; m < WMF; m++) {
      int row = wr * (WMF * 16) + m * 16 + lr;
      int idx = (row * 32 + kf * 8) ^ (((row >> 1) & 3) << 3);
      av[m] = *(const short8*)&As[cur][idx];
    }
#pragma unroll
    for (int n = 0; n < 4; n++) {
      int row = wc * 64 + n * 16 + lr;
      int idx = (row * 32 + kf * 8) ^ (((row >> 1) & 3) << 3);
      bv[n] = *(const short8*)&Bs[cur][idx];
    }
    __builtin_amdgcn_s_setprio(1);
#pragma unroll
    for (int m = 0; m < WMF; m++)
#pragma unroll
      for (int n = 0; n < 4; n++) acc[m][n] = MFMA16(av[m], bv[n], acc[m][n]);
    __builtin_amdgcn_s_setprio(0);
    __builtin_amdgcn_s_barrier();   // reads of cur done before it gets restaged
  }

  // Epilogue. C/D layout: col = lane&15, row = (lane>>4)*4 + i  [m89-verified]
  if constexpr (MODE == 0) {
#pragma unroll
    for (int n = 0; n < 4; n++) {
      int c = colbase + wc * 64 + n * 16 + lr;   // 0..3071
      int sel = c >> 10;                          // 0=Q 1=K 2=V (uniform per n)
      int hh = (c >> 6) & 15;
      int dd = c & 63;
      unsigned short* dst = (sel == 0) ? Qo : ((sel == 1) ? Ko : Vo);
      // fold softmax scale (1/8) and log2(e) into Q so attn uses exp2 directly
      const float sc = (sel == 0) ? 0.18033688011112042f : 1.0f;
#pragma unroll
      for (int m = 0; m < WMF; m++) {
        int r0 = rowbase + wr * (WMF * 16) + m * 16 + kf * 4;
#pragma unroll
        for (int i = 0; i < 4; i++) {
          int r = r0 + i;
          int bi = r >> 11;         // batch
          int tq = r & 2047;        // token
          size_t off = ((size_t)(bi * NH + hh) * SEQ + tq) * HD + dd;  // uniform, coalesced
          dst[off] = f2bf(acc[m][n][i] * sc);
        }
      }
    }
  } else {
#pragma unroll
    for (int n = 0; n < 4; n++) {
      int c = colbase + wc * 64 + n * 16 + lr;
      float bias = bo[c];
#pragma unroll
      for (int m = 0; m < WMF; m++) {
        int r0 = rowbase + wr * (WMF * 16) + m * 16 + kf * 4;
#pragma unroll
        for (int i = 0; i < 4; i++) {
          out[(size_t)(r0 + i) * 1024 + c] = acc[m][n][i] + bias;
        }
      }
    }
  }
}

// ---------------- flash attention (swapped 32x32, static softmax, 32KB dbuf) ----------------
// grid: x = b*H (32), y = 16 -> qt (heavy first). 256 thr, 4 waves.
// Wave w owns q rows [qt*128 + w*32, +32). One 64-k tile per barrier, dbuf.
// LDS 32KB -> 5 blocks/CU (20 waves/CU ceiling).
__global__ __launch_bounds__(256) void attn_fwd(
    const unsigned short* __restrict__ Q, const unsigned short* __restrict__ K,
    const unsigned short* __restrict__ Vt, unsigned short* __restrict__ ctx) {
  const int bh = blockIdx.x;
  const int y = blockIdx.y;
  const int qt = (y < 8) ? (15 - y) : (y - 8);   // heavy q-tiles dispatched first
  const int bi = bh >> 4, hh = bh & 15;
  const int t = threadIdx.x, lane = t & 63, w = t >> 6;
  const int qc = lane & 31, hi = lane >> 5;

  __shared__ __align__(16) unsigned short Ks[2][64 * 64];
  __shared__ __align__(16) unsigned short Vs[2][64 * 64];   // [d][k] swizzled

  const unsigned short* Qb = Q + (size_t)bh * SEQ * HD;
  const unsigned short* Kb = K + (size_t)bh * SEQ * HD;
  const unsigned short* Vb = Vt + (size_t)bh * HD * SEQ;

  const int qrow = qt * 128 + w * 32;
  short8 qv[4];
#pragma unroll
  for (int c = 0; c < 4; c++)
    qv[c] = *(const short8*)&Qb[(size_t)(qrow + qc) * HD + c * 16 + hi * 8];

  f32x16 o0, o1;                    // O^T[d][q]: o0 = d 0..31, o1 = 32..63
#pragma unroll
  for (int i = 0; i < 16; i++) { o0[i] = 0.f; o1[i] = 0.f; }
  float l_acc = 0.f;

  const int ktmax = 2 * qt + (w >> 1);   // this wave's diagonal tile
  const int KT = 2 * qt + 2;             // block-wide tile count

  // stage tile kt into dbuf buf: 512 16B chunks each for K and V, 256 thr x 2.
  // physical chunk f holds logical chunk c = f ^ ((f>>3)&7); reads XOR back.
  auto stage = [&](int buf, int kt) {
#pragma unroll
    for (int i2 = 0; i2 < 2; i2++) {
      int f = i2 * 256 + t;
      int c = f ^ ((f >> 3) & 7);
      async16(Kb + (size_t)kt * 64 * HD + (size_t)c * 8,
              (char*)&Ks[buf][0] + (size_t)f * 16);
      int d = c >> 3, ko = (c & 7) << 3;
      async16(Vb + (size_t)d * SEQ + (size_t)kt * 64 + ko,
              (char*)&Vs[buf][0] + (size_t)f * 16);
    }
  };

  // one 64-k tile: QK^T -> (mask) -> exp2 -> pack -> PV  (R6-proven math)
  auto tile = [&](const unsigned short* Kt, const unsigned short* Vtile, int kt) {
    f32x16 s0, s1;
#pragma unroll
    for (int i = 0; i < 16; i++) { s0[i] = 0.f; s1[i] = 0.f; }
    __builtin_amdgcn_s_setprio(1);
#pragma unroll
    for (int c = 0; c < 4; c++) {
      int i0 = (qc * 64 + c * 16 + hi * 8) ^ ((qc & 7) << 3);
      s0 = MFMA32(*(const short8*)&Kt[i0], qv[c], s0);
      int r1 = 32 + qc;
      int i1 = (r1 * 64 + c * 16 + hi * 8) ^ ((r1 & 7) << 3);
      s1 = MFMA32(*(const short8*)&Kt[i1], qv[c], s1);
    }
    __builtin_amdgcn_s_setprio(0);

    if (kt == ktmax) {               // causal mask, diagonal tile only
      const int qg = qrow + qc;
#pragma unroll
      for (int reg = 0; reg < 16; reg++) {
        int rloc = (reg & 3) + 8 * (reg >> 2) + 4 * hi;
        int kg = kt * 64 + rloc;
        if (kg > qg) s0[reg] = -1e30f;
        if (kg + 32 > qg) s1[reg] = -1e30f;
      }
    }

    unsigned w0[8], w1[8];
    float psA = 0.f, psB = 0.f;
#pragma unroll
    for (int j = 0; j < 8; j++) {
      float a0 = exp2x(s0[2 * j]), b0 = exp2x(s0[2 * j + 1]);
      float a1 = exp2x(s1[2 * j]), b1 = exp2x(s1[2 * j + 1]);
      psA += a0 + b0;
      psB += a1 + b1;
      w0[j] = cvt_pk(a0, b0);
      w1[j] = cvt_pk(a1, b1);
    }
    l_acc += psA + psB;

    __builtin_amdgcn_s_setprio(1);
#pragma unroll
    for (int h2 = 0; h2 < 2; h2++) {
      unsigned* pw = h2 ? w1 : w0;
#pragma unroll
      for (int cc = 0; cc < 2; cc++) {
        unsigned a0 = pw[cc * 4 + 0], b0 = pw[cc * 4 + 2];
        unsigned a1 = pw[cc * 4 + 1], b1 = pw[cc * 4 + 3];
        pls(a0, b0);                 // (pf0,pf2) both halves in one instr
        pls(a1, b1);                 // (pf1,pf3)
        u32x4 pf; pf[0] = a0; pf[1] = a1; pf[2] = b0; pf[3] = b1;
        short8 pfrag = as_short8(pf);
        int c2 = h2 * 2 + cc;
        int ia = (qc * 64 + c2 * 16 + hi * 8) ^ ((qc & 7) << 3);
        o0 = MFMA32(*(const short8*)&Vtile[ia], pfrag, o0);
        int rb = 32 + qc;
        int ib = (rb * 64 + c2 * 16 + hi * 8) ^ ((rb & 7) << 3);
        o1 = MFMA32(*(const short8*)&Vtile[ib], pfrag, o1);
      }
    }
    __builtin_amdgcn_s_setprio(0);
  };

  stage(0, 0);
  int cur = 0;

  for (int kt = 0; kt < KT; kt++) {
    if (kt + 1 < KT) {
      stage(cur ^ 1, kt + 1);
      asm volatile("s_waitcnt vmcnt(4)" ::: "memory");  // tile kt landed; kt+1 in flight
    } else {
      asm volatile("s_waitcnt vmcnt(0)" ::: "memory");
    }
    __builtin_amdgcn_s_barrier();

    if (kt <= ktmax) tile(&Ks[cur][0], &Vs[cur][0], kt);

    __builtin_amdgcn_s_barrier();   // all waves done reading cur before restage
    cur ^= 1;
  }

  // epilogue: l = in-lane sum + one cross-half swap; O/l -> ctx
  float l = l_acc + __shfl_xor(l_acc, 32);
  float inv = 1.0f / l;
  const size_t rowoff = ((size_t)bi * SEQ + qrow + qc) * DMODEL + hh * HD;
#pragma unroll
  for (int g = 0; g < 4; g++) {
    unsigned pa = cvt_pk(o0[4 * g] * inv, o0[4 * g + 1] * inv);
    unsigned pb = cvt_pk(o0[4 * g + 2] * inv, o0[4 * g + 3] * inv);
    uint2 vv; vv.x = pa; vv.y = pb;
    *(uint2*)&ctx[rowoff + 8 * g + 4 * hi] = vv;
    unsigned pc = cvt_pk(o1[4 * g] * inv, o1[4 * g + 1] * inv);
    unsigned pd = cvt_pk(o1[4 * g + 2] * inv, o1[4 * g + 3] * inv);
    uint2 ww; ww.x = pc; ww.y = pd;
    *(uint2*)&ctx[rowoff + 32 + 8 * g + 4 * hi] = ww;
  }
}

// ---------------- launch ----------------
extern "C" void kernel_launch(void* const* d_in, const int* in_sizes, int n_in,
                              void* d_out, int out_size, void* d_ws, size_t ws_size,
                              hipStream_t stream) {
  const float* x  = (const float*)d_in[0];
  const float* Wq = (const float*)d_in[1];
  const float* Wk = (const float*)d_in[2];
  const float* Wv = (const float*)d_in[3];
  const float* Wo = (const float*)d_in[4];
  const float* bo = (const float*)d_in[5];
  float* out = (float*)d_out;

  unsigned short* xb   = (unsigned short*)d_ws;                 // 4M elems
  unsigned short* Wt   = xb + (size_t)MROWS * DMODEL;           // 3M (Wq^T|Wk^T|Wv^T)
  unsigned short* WoT  = Wt + (size_t)3 * 1024 * 1024;          // 1M
  unsigned short* Qb   = WoT + (size_t)1024 * 1024;             // 4M
  unsigned short* Kb   = Qb + (size_t)MROWS * DMODEL;           // 4M
  unsigned short* Vb   = Kb + (size_t)MROWS * DMODEL;           // 4M  V^T [b,h,d,t]
  unsigned short* ctxb = Vb + (size_t)MROWS * DMODEL;           // 4M  (aliased: V normal pre-vtrans, ctx post-attn)

  prep<<<3072, 256, 0, stream>>>(x, Wq, Wk, Wv, Wo, xb, Wt, WoT);

  // V written un-transposed into ctxb slot, then transposed into Vb
  gemm_bt<0, 4><<<dim3(32, 24), 256, 0, stream>>>(xb, Wt, Qb, Kb, ctxb, nullptr, nullptr);
  vtrans<<<dim3(32, 32), 256, 0, stream>>>(ctxb, Vb);
  attn_fwd<<<dim3(32, 16), 256, 0, stream>>>(Qb, Kb, Vb, ctxb);
  gemm_bt<1, 2><<<dim3(64, 8), 256, 0, stream>>>(ctxb, WoT, nullptr, nullptr, nullptr, out, bo);
}

// Round 11
// 106.198 us; speedup vs baseline: 1.3837x; 1.1377x over previous
//
#include <hip/hip_runtime.h>

// MHA forward, MI355X gfx950.
// R11: attn reverted to R6-proven paired-subtile form (42.4us). vtrans deleted:
//      QKV GEMM epilogue transposes V in (dead) pipeline LDS and stores V^T
//      coalesced. prep merge kept.

#define SEQ   2048
#define DMODEL 1024
#define NH    16
#define HD    64
#define MROWS 4096   // b*t = 2*2048

typedef __attribute__((ext_vector_type(4))) float f32x4;
typedef __attribute__((ext_vector_type(16))) float f32x16;
typedef __attribute__((ext_vector_type(8))) short short8;
typedef __attribute__((ext_vector_type(4))) unsigned int u32x4;

#define MFMA16(a, b, c) __builtin_amdgcn_mfma_f32_16x16x32_bf16((a), (b), (c), 0, 0, 0)
#define MFMA32(a, b, c) __builtin_amdgcn_mfma_f32_32x32x16_bf16((a), (b), (c), 0, 0, 0)

__device__ __forceinline__ unsigned short f2bf(float f) {
  union { float f; unsigned u; } v; v.f = f;
  return (unsigned short)((v.u + 0x7fffu + ((v.u >> 16) & 1u)) >> 16);
}

__device__ __forceinline__ float exp2x(float x) {
#if __has_builtin(__builtin_amdgcn_exp2f)
  return __builtin_amdgcn_exp2f(x);
#else
  float r; asm("v_exp_f32 %0, %1" : "=v"(r) : "v"(x)); return r;
#endif
}

__device__ __forceinline__ unsigned cvt_pk(float lo, float hi) {
  unsigned r;
  asm volatile("v_cvt_pk_bf16_f32 %0, %1, %2" : "=v"(r) : "v"(lo), "v"(hi));
  return r;
}

// v_permlane32_swap: a' = [a.lo | b.lo-in-hi-lanes], b' = [a.hi-in-lo-lanes | b.hi]
__device__ __forceinline__ void pls(unsigned& a, unsigned& b) {
  asm("v_permlane32_swap_b32 %0, %1" : "+v"(a), "+v"(b));
}

__device__ __forceinline__ short8 as_short8(u32x4 v) {
  union { u32x4 u; short8 s; } x; x.u = v; return x.s;
}

__device__ __forceinline__ f32x4 zero4() {
  f32x4 z; z[0] = 0.f; z[1] = 0.f; z[2] = 0.f; z[3] = 0.f; return z;
}

// async global->LDS, 16B per lane, linear dest (wave base + lane*16)
__device__ __forceinline__ void async16(const void* g, void* l) {
  __builtin_amdgcn_global_load_lds(
      (const __attribute__((address_space(1))) unsigned int*)g,
      (__attribute__((address_space(3))) unsigned int*)l, 16, 0, 0);
}

// ---------------- prep: x->bf16 (blocks 0..2047) + 4x W transpose (2048..3071) ----------------
__global__ __launch_bounds__(256) void prep(
    const float* __restrict__ x, const float* __restrict__ Wq,
    const float* __restrict__ Wk, const float* __restrict__ Wv,
    const float* __restrict__ Wo, unsigned short* __restrict__ xb,
    unsigned short* __restrict__ Wt, unsigned short* __restrict__ WoT) {
  __shared__ unsigned short tile[64][65];
  const int bx = blockIdx.x;
  if (bx < 2048) {
    int i = bx * 256 + threadIdx.x;            // handles 8 elements
    const float4* p = (const float4*)x;
    float4 a = p[2 * i];
    float4 b = p[2 * i + 1];
    short8 o;
    o[0] = (short)f2bf(a.x); o[1] = (short)f2bf(a.y);
    o[2] = (short)f2bf(a.z); o[3] = (short)f2bf(a.w);
    o[4] = (short)f2bf(b.x); o[5] = (short)f2bf(b.y);
    o[6] = (short)f2bf(b.z); o[7] = (short)f2bf(b.w);
    *(short8*)&xb[(size_t)i * 8] = o;
    return;
  }
  const int id2 = bx - 2048;
  const int m = id2 >> 8;                      // which matrix
  const float* W = (m == 0) ? Wq : (m == 1) ? Wk : (m == 2) ? Wv : Wo;
  unsigned short* D = (m == 3) ? WoT : Wt + (size_t)m * 1024 * 1024;
  const int tid = id2 & 255;
  const int kb = (tid >> 4) * 64, nb = (tid & 15) * 64;
  const int t = threadIdx.x;
  const int tx = t & 63, ty = t >> 6;          // ty 0..3
#pragma unroll
  for (int rr = 0; rr < 16; rr++) {
    int r = ty * 16 + rr;
    tile[r][tx] = f2bf(W[(size_t)(kb + r) * 1024 + nb + tx]);
  }
  __syncthreads();
#pragma unroll
  for (int rr = 0; rr < 16; rr++) {
    int r = ty * 16 + rr;
    D[(size_t)(nb + r) * 1024 + kb + tx] = tile[tx][r];
  }
}

// ---------------- GEMM: C[M,N] = A[M,1024] * Bt[N,1024]^T ----------------
// BM = WMF*32 rows, 128 cols, BK=32, 256 threads (4 waves, 2x2), WMFx4 frags/wave.
// 3-buffer 2-deep pipeline, counted vmcnt, raw barriers, chunk-XOR LDS swizzle,
// XCD swizzle.
// MODE 0: Q (pre-scaled 0.125*log2e) / K stored [b,h,t,d]; V-blocks transpose
//         their 128x128 tile in the (dead) pipeline LDS and store V^T [b,h,d,t]
//         coalesced (replaces the vtrans kernel).
// MODE 1: out[r*1024+c] = acc + bo[c]  (fp32)
template <int MODE, int WMF>
__global__ __launch_bounds__(256) void gemm_bt(
    const unsigned short* __restrict__ A, const unsigned short* __restrict__ Bt,
    unsigned short* __restrict__ Qo, unsigned short* __restrict__ Ko,
    unsigned short* __restrict__ Vo, float* __restrict__ out,
    const float* __restrict__ bo) {
  constexpr int K = 1024;
  constexpr int BM = WMF * 32;
  constexpr int NT = K / 32;                    // 32 k-tiles
  // single pool: pipeline As[3][BM*32] | Bs[3][128*32]; epilogue reuses as [128][136]
  __shared__ __align__(16) unsigned short smem[3 * BM * 32 + 3 * 128 * 32];
  unsigned short* Asb = smem;
  unsigned short* Bsb = smem + 3 * BM * 32;
  const int t = threadIdx.x;
  const int lane = t & 63;
  const int w = t >> 6;
  const int lr = lane & 15, kf = lane >> 4;
  const int wr = w >> 1, wc = w & 1;

  // XCD-aware swizzle (8 XCDs; nwg multiple of 8)
  const int nwg = gridDim.x * gridDim.y;
  const int id = blockIdx.y * gridDim.x + blockIdx.x;
  const int swz = (id & 7) * (nwg >> 3) + (id >> 3);
  const int bx = swz % gridDim.x, by = swz / gridDim.x;

  const int rowbase = bx * BM;
  const int colbase = by * 128;

  const unsigned short* Ab = A + (size_t)rowbase * K;
  const unsigned short* Bb = Bt + (size_t)colbase * K;

  f32x4 acc[WMF][4];
#pragma unroll
  for (int m = 0; m < WMF; m++)
#pragma unroll
    for (int n = 0; n < 4; n++) acc[m][n] = zero4();

  // physical 16B chunk f takes global data of logical chunk c = f ^ ((f>>3)&3)
  auto stage = [&](int buf, int kt) {
    int k0 = kt * 32;
#pragma unroll
    for (int i = 0; i < BM / 64; i++) {
      int f = i * 256 + t;          // A physical chunk id
      int c = f ^ ((f >> 3) & 3);
      int row = c >> 2;             // 4 chunks per 32-elem row
      int col = (c & 3) << 3;
      async16(Ab + (size_t)row * K + k0 + col,
              (char*)(Asb + (size_t)buf * BM * 32) + (size_t)f * 16);
    }
#pragma unroll
    for (int i = 0; i < 2; i++) {
      int f = i * 256 + t;          // B physical chunk id, 0..511
      int c = f ^ ((f >> 3) & 3);
      int row = c >> 2;
      int col = (c & 3) << 3;
      async16(Bb + (size_t)row * K + k0 + col,
              (char*)(Bsb + (size_t)buf * 128 * 32) + (size_t)f * 16);
    }
  };

  stage(0, 0);
  stage(1, 1);

  for (int kt = 0; kt < NT; kt++) {
    if (kt + 2 < NT) {
      stage((kt + 2) % 3, kt + 2);  // two stages in flight beyond current
      if constexpr (MODE == 0) asm volatile("s_waitcnt vmcnt(8)" ::: "memory");
      else                     asm volatile("s_waitcnt vmcnt(6)" ::: "memory");
    } else if (kt + 1 < NT) {
      if constexpr (MODE == 0) asm volatile("s_waitcnt vmcnt(4)" ::: "memory");
      else                     asm volatile("s_waitcnt vmcnt(3)" ::: "memory");
    } else {
      asm volatile("s_waitcnt vmcnt(0)" ::: "memory");
    }
    __builtin_amdgcn_s_barrier();   // all waves' current-tile loads landed

    const unsigned short* As = Asb + (size_t)(kt % 3) * BM * 32;
    const unsigned short* Bs = Bsb + (size_t)(kt % 3) * 128 * 32;
    short8 av[WMF], bv[4];
#pragma unroll
    for (int m = 0; m < WMF; m++) {
      int row = wr * (WMF * 16) + m * 16 + lr;
      int idx = (row * 32 + kf * 8) ^ (((row >> 1) & 3) << 3);
      av[m] = *(const short8*)&As[idx];
    }
#pragma unroll
    for (int n = 0; n < 4; n++) {
      int row = wc * 64 + n * 16 + lr;
      int idx = (row * 32 + kf * 8) ^ (((row >> 1) & 3) << 3);
      bv[n] = *(const short8*)&Bs[idx];
    }
    __builtin_amdgcn_s_setprio(1);
#pragma unroll
    for (int m = 0; m < WMF; m++)
#pragma unroll
      for (int n = 0; n < 4; n++) acc[m][n] = MFMA16(av[m], bv[n], acc[m][n]);
    __builtin_amdgcn_s_setprio(0);
    __builtin_amdgcn_s_barrier();   // reads of cur done before it gets restaged
  }

  // Epilogue. C/D layout: col = lane&15, row = (lane>>4)*4 + i  [m89-verified]
  if constexpr (MODE == 0) {
    if (colbase < 2048) {
      // Q or K block (tiles never cross the 1024 boundary)
      const int selq = colbase >> 10;              // 0=Q 1=K
      unsigned short* dst = selq ? Ko : Qo;
      const float sc = selq ? 1.0f : 0.18033688011112042f;  // 0.125*log2e into Q
#pragma unroll
      for (int n = 0; n < 4; n++) {
        int c = colbase + wc * 64 + n * 16 + lr;
        int hh = (c >> 6) & 15;
        int dd = c & 63;
#pragma unroll
        for (int m = 0; m < WMF; m++) {
          int r0 = rowbase + wr * (WMF * 16) + m * 16 + kf * 4;
#pragma unroll
          for (int i = 0; i < 4; i++) {
            int r = r0 + i;
            int bi = r >> 11;
            int tq = r & 2047;
            dst[((size_t)(bi * NH + hh) * SEQ + tq) * HD + dd] = f2bf(acc[m][n][i] * sc);
          }
        }
      }
    } else {
      // V block: transpose tile in LDS (dead pipeline buffers), store V^T coalesced.
      unsigned short* tr = smem;                   // [128 col][136]
#pragma unroll
      for (int n = 0; n < 4; n++) {
        int ccol = wc * 64 + n * 16 + lr;
#pragma unroll
        for (int m = 0; m < WMF; m++) {
#pragma unroll
          for (int i = 0; i < 4; i++) {
            int rrow = wr * (WMF * 16) + m * 16 + kf * 4 + i;
            tr[ccol * 136 + rrow] = f2bf(acc[m][n][i]);
          }
        }
      }
      __syncthreads();
      const int bi2 = rowbase >> 11;
      const int tq0 = rowbase & 2047;
#pragma unroll
      for (int k2 = 0; k2 < 8; k2++) {
        int u = k2 * 256 + t;                      // 2048 units: [col][seg of 8]
        int cc = u >> 4, seg = u & 15;
        int c = colbase + cc;
        int hh = (c >> 6) & 15, dd = c & 63;
        short8 v8 = *(const short8*)&tr[cc * 136 + seg * 8];
        *(short8*)&Vo[((size_t)(bi2 * NH + hh) * HD + dd) * SEQ + tq0 + seg * 8] = v8;
      }
    }
  } else {
#pragma unroll
    for (int n = 0; n < 4; n++) {
      int c = colbase + wc * 64 + n * 16 + lr;
      float bias = bo[c];
#pragma unroll
      for (int m = 0; m < WMF; m++) {
        int r0 = rowbase + wr * (WMF * 16) + m * 16 + kf * 4;
#pragma unroll
        for (int i = 0; i < 4; i++) {
          out[(size_t)(r0 + i) * 1024 + c] = acc[m][n][i] + bias;
        }
      }
    }
  }
}

// ---------------- flash attention (R6-proven: swapped 32x32, static softmax, paired tiles) ----
// grid: x = b*H (32), y -> qt via CU-pair-balanced remap. 256 thr, 4 waves.
// Wave w owns q rows [qt*128 + w*32, +32). k processed as pairs of 64-subtiles.
__global__ __launch_bounds__(256) void attn_fwd(
    const unsigned short* __restrict__ Q, const unsigned short* __restrict__ K,
    const unsigned short* __restrict__ Vt, unsigned short* __restrict__ ctx) {
  const int bh = blockIdx.x;
  const int y = blockIdx.y;
  const int qt = (y < 8) ? (15 - y) : (y - 8);   // co-resident pairs sum to 36 k-tiles
  const int bi = bh >> 4, hh = bh & 15;
  const int t = threadIdx.x, lane = t & 63, w = t >> 6;
  const int qc = lane & 31, hi = lane >> 5;

  __shared__ __align__(16) unsigned short Ks[2][2][64 * 64];   // [dbuf][sub]
  __shared__ __align__(16) unsigned short Vs[2][2][64 * 64];   // [d][k] swizzled

  const unsigned short* Qb = Q + (size_t)bh * SEQ * HD;
  const unsigned short* Kb = K + (size_t)bh * SEQ * HD;
  const unsigned short* Vb = Vt + (size_t)bh * HD * SEQ;

  const int qrow = qt * 128 + w * 32;
  short8 qv[4];
#pragma unroll
  for (int c = 0; c < 4; c++)
    qv[c] = *(const short8*)&Qb[(size_t)(qrow + qc) * HD + c * 16 + hi * 8];

  f32x16 o0, o1;                    // O^T[d][q]: o0 = d 0..31, o1 = 32..63
#pragma unroll
  for (int i = 0; i < 16; i++) { o0[i] = 0.f; o1[i] = 0.f; }
  float l_acc = 0.f;

  const int ktmax = 2 * qt + (w >> 1);   // last k-tile this wave needs
  const int NP = qt + 1;                 // pairs of 64-k subtiles

  // stage pair p into dbuf buf: two 64-subtiles, proven swizzle
  // (physical 16B chunk f holds logical chunk f ^ ((f>>3)&7); reads XOR back)
  auto stage = [&](int buf, int p) {
#pragma unroll
    for (int sub = 0; sub < 2; sub++) {
      int kt = 2 * p + sub;
#pragma unroll
      for (int i2 = 0; i2 < 2; i2++) {
        int f = i2 * 256 + t;
        int c = f ^ ((f >> 3) & 7);
        async16(Kb + (size_t)kt * 64 * HD + (size_t)c * 8,
                (char*)&Ks[buf][sub][0] + (size_t)f * 16);
        int d = c >> 3, ko = (c & 7) << 3;
        async16(Vb + (size_t)d * SEQ + (size_t)kt * 64 + ko,
                (char*)&Vs[buf][sub][0] + (size_t)f * 16);
      }
    }
  };

  // one 64-k subtile: QK^T -> (mask) -> exp2 -> pack -> PV
  auto tile = [&](const unsigned short* Kt, const unsigned short* Vtile, int kt) {
    f32x16 s0, s1;
#pragma unroll
    for (int i = 0; i < 16; i++) { s0[i] = 0.f; s1[i] = 0.f; }
    __builtin_amdgcn_s_setprio(1);
#pragma unroll
    for (int c = 0; c < 4; c++) {
      int i0 = (qc * 64 + c * 16 + hi * 8) ^ ((qc & 7) << 3);
      s0 = MFMA32(*(const short8*)&Kt[i0], qv[c], s0);
      int r1 = 32 + qc;
      int i1 = (r1 * 64 + c * 16 + hi * 8) ^ ((r1 & 7) << 3);
      s1 = MFMA32(*(const short8*)&Kt[i1], qv[c], s1);
    }
    __builtin_amdgcn_s_setprio(0);

    if (kt == ktmax) {               // causal mask, diagonal tile only
      const int qg = qrow + qc;
#pragma unroll
      for (int reg = 0; reg < 16; reg++) {
        int rloc = (reg & 3) + 8 * (reg >> 2) + 4 * hi;
        int kg = kt * 64 + rloc;
        if (kg > qg) s0[reg] = -1e30f;
        if (kg + 32 > qg) s1[reg] = -1e30f;
      }
    }

    unsigned w0[8], w1[8];
    float psA = 0.f, psB = 0.f;
#pragma unroll
    for (int j = 0; j < 8; j++) {
      float a0 = exp2x(s0[2 * j]), b0 = exp2x(s0[2 * j + 1]);
      float a1 = exp2x(s1[2 * j]), b1 = exp2x(s1[2 * j + 1]);
      psA += a0 + b0;
      psB += a1 + b1;
      w0[j] = cvt_pk(a0, b0);
      w1[j] = cvt_pk(a1, b1);
    }
    l_acc += psA + psB;

    __builtin_amdgcn_s_setprio(1);
#pragma unroll
    for (int h2 = 0; h2 < 2; h2++) {
      unsigned* pw = h2 ? w1 : w0;
#pragma unroll
      for (int cc = 0; cc < 2; cc++) {
        unsigned a0 = pw[cc * 4 + 0], b0 = pw[cc * 4 + 2];
        unsigned a1 = pw[cc * 4 + 1], b1 = pw[cc * 4 + 3];
        pls(a0, b0);                 // (pf0,pf2) both halves in one instr
        pls(a1, b1);                 // (pf1,pf3)
        u32x4 pf; pf[0] = a0; pf[1] = a1; pf[2] = b0; pf[3] = b1;
        short8 pfrag = as_short8(pf);
        int c2 = h2 * 2 + cc;
        int ia = (qc * 64 + c2 * 16 + hi * 8) ^ ((qc & 7) << 3);
        o0 = MFMA32(*(const short8*)&Vtile[ia], pfrag, o0);
        int rb = 32 + qc;
        int ib = (rb * 64 + c2 * 16 + hi * 8) ^ ((rb & 7) << 3);
        o1 = MFMA32(*(const short8*)&Vtile[ib], pfrag, o1);
      }
    }
    __builtin_amdgcn_s_setprio(0);
  };

  stage(0, 0);
  int cur = 0;

  for (int p = 0; p < NP; p++) {
    if (p + 1 < NP) {
      stage(cur ^ 1, p + 1);
      asm volatile("s_waitcnt vmcnt(8)" ::: "memory");  // pair p landed; next in flight
    } else {
      asm volatile("s_waitcnt vmcnt(0)" ::: "memory");
    }
    __builtin_amdgcn_s_barrier();

    if (2 * p <= ktmax)     tile(&Ks[cur][0][0], &Vs[cur][0][0], 2 * p);
    if (2 * p + 1 <= ktmax) tile(&Ks[cur][1][0], &Vs[cur][1][0], 2 * p + 1);

    __builtin_amdgcn_s_barrier();
    cur ^= 1;
  }

  // epilogue: l = in-lane sum + one cross-half swap; O/l -> ctx
  float l = l_acc + __shfl_xor(l_acc, 32);
  float inv = 1.0f / l;
  const size_t rowoff = ((size_t)bi * SEQ + qrow + qc) * DMODEL + hh * HD;
#pragma unroll
  for (int g = 0; g < 4; g++) {
    unsigned pa = cvt_pk(o0[4 * g] * inv, o0[4 * g + 1] * inv);
    unsigned pb = cvt_pk(o0[4 * g + 2] * inv, o0[4 * g + 3] * inv);
    uint2 vv; vv.x = pa; vv.y = pb;
    *(uint2*)&ctx[rowoff + 8 * g + 4 * hi] = vv;
    unsigned pc = cvt_pk(o1[4 * g] * inv, o1[4 * g + 1] * inv);
    unsigned pd = cvt_pk(o1[4 * g + 2] * inv, o1[4 * g + 3] * inv);
    uint2 ww; ww.x = pc; ww.y = pd;
    *(uint2*)&ctx[rowoff + 32 + 8 * g + 4 * hi] = ww;
  }
}

// ---------------- launch ----------------
extern "C" void kernel_launch(void* const* d_in, const int* in_sizes, int n_in,
                              void* d_out, int out_size, void* d_ws, size_t ws_size,
                              hipStream_t stream) {
  const float* x  = (const float*)d_in[0];
  const float* Wq = (const float*)d_in[1];
  const float* Wk = (const float*)d_in[2];
  const float* Wv = (const float*)d_in[3];
  const float* Wo = (const float*)d_in[4];
  const float* bo = (const float*)d_in[5];
  float* out = (float*)d_out;

  unsigned short* xb   = (unsigned short*)d_ws;                 // 4M elems
  unsigned short* Wt   = xb + (size_t)MROWS * DMODEL;           // 3M (Wq^T|Wk^T|Wv^T)
  unsigned short* WoT  = Wt + (size_t)3 * 1024 * 1024;          // 1M
  unsigned short* Qb   = WoT + (size_t)1024 * 1024;             // 4M
  unsigned short* Kb   = Qb + (size_t)MROWS * DMODEL;           // 4M
  unsigned short* Vb   = Kb + (size_t)MROWS * DMODEL;           // 4M  V^T [b,h,d,t]
  unsigned short* ctxb = Vb + (size_t)MROWS * DMODEL;           // 4M

  prep<<<3072, 256, 0, stream>>>(x, Wq, Wk, Wv, Wo, xb, Wt, WoT);

  gemm_bt<0, 4><<<dim3(32, 24), 256, 0, stream>>>(xb, Wt, Qb, Kb, Vb, nullptr, nullptr);
  attn_fwd<<<dim3(32, 16), 256, 0, stream>>>(Qb, Kb, Vb, ctxb);
  gemm_bt<1, 2><<<dim3(64, 8), 256, 0, stream>>>(ctxb, WoT, nullptr, nullptr, nullptr, out, bo);
}

// Round 12
// 104.777 us; speedup vs baseline: 1.4024x; 1.0136x over previous
//
#include <hip/hip_runtime.h>

// MHA forward, MI355X gfx950.
// R12: gemm_bt gets paired k-windows (2x32-k subtiles per barrier, 2x2 LDS
//      buffers, counted vmcnt) — same barrier-amortization that won R6's attn.
//      attn (R6-proven) / prep / V^T-epilogue unchanged from R11.

#define SEQ   2048
#define DMODEL 1024
#define NH    16
#define HD    64
#define MROWS 4096   // b*t = 2*2048

typedef __attribute__((ext_vector_type(4))) float f32x4;
typedef __attribute__((ext_vector_type(16))) float f32x16;
typedef __attribute__((ext_vector_type(8))) short short8;
typedef __attribute__((ext_vector_type(4))) unsigned int u32x4;

#define MFMA16(a, b, c) __builtin_amdgcn_mfma_f32_16x16x32_bf16((a), (b), (c), 0, 0, 0)
#define MFMA32(a, b, c) __builtin_amdgcn_mfma_f32_32x32x16_bf16((a), (b), (c), 0, 0, 0)

__device__ __forceinline__ unsigned short f2bf(float f) {
  union { float f; unsigned u; } v; v.f = f;
  return (unsigned short)((v.u + 0x7fffu + ((v.u >> 16) & 1u)) >> 16);
}

__device__ __forceinline__ float exp2x(float x) {
#if __has_builtin(__builtin_amdgcn_exp2f)
  return __builtin_amdgcn_exp2f(x);
#else
  float r; asm("v_exp_f32 %0, %1" : "=v"(r) : "v"(x)); return r;
#endif
}

__device__ __forceinline__ unsigned cvt_pk(float lo, float hi) {
  unsigned r;
  asm volatile("v_cvt_pk_bf16_f32 %0, %1, %2" : "=v"(r) : "v"(lo), "v"(hi));
  return r;
}

// v_permlane32_swap: a' = [a.lo | b.lo-in-hi-lanes], b' = [a.hi-in-lo-lanes | b.hi]
__device__ __forceinline__ void pls(unsigned& a, unsigned& b) {
  asm("v_permlane32_swap_b32 %0, %1" : "+v"(a), "+v"(b));
}

__device__ __forceinline__ short8 as_short8(u32x4 v) {
  union { u32x4 u; short8 s; } x; x.u = v; return x.s;
}

__device__ __forceinline__ f32x4 zero4() {
  f32x4 z; z[0] = 0.f; z[1] = 0.f; z[2] = 0.f; z[3] = 0.f; return z;
}

// async global->LDS, 16B per lane, linear dest (wave base + lane*16)
__device__ __forceinline__ void async16(const void* g, void* l) {
  __builtin_amdgcn_global_load_lds(
      (const __attribute__((address_space(1))) unsigned int*)g,
      (__attribute__((address_space(3))) unsigned int*)l, 16, 0, 0);
}

// ---------------- prep: x->bf16 (blocks 0..2047) + 4x W transpose (2048..3071) ----------------
__global__ __launch_bounds__(256) void prep(
    const float* __restrict__ x, const float* __restrict__ Wq,
    const float* __restrict__ Wk, const float* __restrict__ Wv,
    const float* __restrict__ Wo, unsigned short* __restrict__ xb,
    unsigned short* __restrict__ Wt, unsigned short* __restrict__ WoT) {
  __shared__ unsigned short tile[64][65];
  const int bx = blockIdx.x;
  if (bx < 2048) {
    int i = bx * 256 + threadIdx.x;            // handles 8 elements
    const float4* p = (const float4*)x;
    float4 a = p[2 * i];
    float4 b = p[2 * i + 1];
    short8 o;
    o[0] = (short)f2bf(a.x); o[1] = (short)f2bf(a.y);
    o[2] = (short)f2bf(a.z); o[3] = (short)f2bf(a.w);
    o[4] = (short)f2bf(b.x); o[5] = (short)f2bf(b.y);
    o[6] = (short)f2bf(b.z); o[7] = (short)f2bf(b.w);
    *(short8*)&xb[(size_t)i * 8] = o;
    return;
  }
  const int id2 = bx - 2048;
  const int m = id2 >> 8;                      // which matrix
  const float* W = (m == 0) ? Wq : (m == 1) ? Wk : (m == 2) ? Wv : Wo;
  unsigned short* D = (m == 3) ? WoT : Wt + (size_t)m * 1024 * 1024;
  const int tid = id2 & 255;
  const int kb = (tid >> 4) * 64, nb = (tid & 15) * 64;
  const int t = threadIdx.x;
  const int tx = t & 63, ty = t >> 6;          // ty 0..3
#pragma unroll
  for (int rr = 0; rr < 16; rr++) {
    int r = ty * 16 + rr;
    tile[r][tx] = f2bf(W[(size_t)(kb + r) * 1024 + nb + tx]);
  }
  __syncthreads();
#pragma unroll
  for (int rr = 0; rr < 16; rr++) {
    int r = ty * 16 + rr;
    D[(size_t)(nb + r) * 1024 + kb + tx] = tile[tx][r];
  }
}

// ---------------- GEMM: C[M,N] = A[M,1024] * Bt[N,1024]^T ----------------
// BM = WMF*32 rows, 128 cols, 256 threads (4 waves, 2x2), WMFx4 frags/wave.
// R12: paired k-windows — 2x 32-k subtiles per barrier (32 MFMA/window), 2x2
// LDS buffers, counted vmcnt (8 / 6), raw barriers, chunk-XOR LDS swizzle,
// XCD swizzle.
// MODE 0: Q (pre-scaled 0.125*log2e) / K stored [b,h,t,d]; V-blocks transpose
//         their tile in (dead) pipeline LDS and store V^T [b,h,d,t] coalesced.
// MODE 1: out[r*1024+c] = acc + bo[c]  (fp32)
template <int MODE, int WMF>
__global__ __launch_bounds__(256) void gemm_bt(
    const unsigned short* __restrict__ A, const unsigned short* __restrict__ Bt,
    unsigned short* __restrict__ Qo, unsigned short* __restrict__ Ko,
    unsigned short* __restrict__ Vo, float* __restrict__ out,
    const float* __restrict__ bo) {
  constexpr int K = 1024;
  constexpr int BM = WMF * 32;
  constexpr int NW = K / 64;                    // 16 windows of 2 subtiles
  constexpr int ASZ = BM * 32;
  constexpr int BSZ = 128 * 32;
  // pool: As[2][2][ASZ] | Bs[2][2][BSZ]; V-epilogue reuses as [128][136]
  __shared__ __align__(16) unsigned short smem[4 * ASZ + 4 * BSZ];
  unsigned short* Asb = smem;
  unsigned short* Bsb = smem + 4 * ASZ;
  const int t = threadIdx.x;
  const int lane = t & 63;
  const int w = t >> 6;
  const int lr = lane & 15, kf = lane >> 4;
  const int wr = w >> 1, wc = w & 1;

  // XCD-aware swizzle (8 XCDs; nwg multiple of 8)
  const int nwg = gridDim.x * gridDim.y;
  const int id = blockIdx.y * gridDim.x + blockIdx.x;
  const int swz = (id & 7) * (nwg >> 3) + (id >> 3);
  const int bx = swz % gridDim.x, by = swz / gridDim.x;

  const int rowbase = bx * BM;
  const int colbase = by * 128;

  const unsigned short* Ab = A + (size_t)rowbase * K;
  const unsigned short* Bb = Bt + (size_t)colbase * K;

  f32x4 acc[WMF][4];
#pragma unroll
  for (int m = 0; m < WMF; m++)
#pragma unroll
    for (int n = 0; n < 4; n++) acc[m][n] = zero4();

  // stage window wi (subtiles 2wi, 2wi+1) into buffer pair buf.
  // physical 16B chunk f takes global data of logical chunk c = f ^ ((f>>3)&3)
  auto stage = [&](int buf, int wi) {
#pragma unroll
    for (int sub = 0; sub < 2; sub++) {
      int k0 = (2 * wi + sub) * 32;
      unsigned short* Ad = Asb + ((size_t)buf * 2 + sub) * ASZ;
      unsigned short* Bd = Bsb + ((size_t)buf * 2 + sub) * BSZ;
#pragma unroll
      for (int i = 0; i < BM / 64; i++) {
        int f = i * 256 + t;          // A physical chunk id
        int c = f ^ ((f >> 3) & 3);
        int row = c >> 2;             // 4 chunks per 32-elem row
        int col = (c & 3) << 3;
        async16(Ab + (size_t)row * K + k0 + col, (char*)Ad + (size_t)f * 16);
      }
#pragma unroll
      for (int i = 0; i < 2; i++) {
        int f = i * 256 + t;          // B physical chunk id, 0..511
        int c = f ^ ((f >> 3) & 3);
        int row = c >> 2;
        int col = (c & 3) << 3;
        async16(Bb + (size_t)row * K + k0 + col, (char*)Bd + (size_t)f * 16);
      }
    }
  };

  // compute one 32-k subtile from staged LDS
  auto compute = [&](int buf, int sub) {
    const unsigned short* As = Asb + ((size_t)buf * 2 + sub) * ASZ;
    const unsigned short* Bs = Bsb + ((size_t)buf * 2 + sub) * BSZ;
    short8 av[WMF], bv[4];
#pragma unroll
    for (int m = 0; m < WMF; m++) {
      int row = wr * (WMF * 16) + m * 16 + lr;
      int idx = (row * 32 + kf * 8) ^ (((row >> 1) & 3) << 3);
      av[m] = *(const short8*)&As[idx];
    }
#pragma unroll
    for (int n = 0; n < 4; n++) {
      int row = wc * 64 + n * 16 + lr;
      int idx = (row * 32 + kf * 8) ^ (((row >> 1) & 3) << 3);
      bv[n] = *(const short8*)&Bs[idx];
    }
    __builtin_amdgcn_s_setprio(1);
#pragma unroll
    for (int m = 0; m < WMF; m++)
#pragma unroll
      for (int n = 0; n < 4; n++) acc[m][n] = MFMA16(av[m], bv[n], acc[m][n]);
    __builtin_amdgcn_s_setprio(0);
  };

  stage(0, 0);
  int cur = 0;

  for (int wi = 0; wi < NW; wi++) {
    if (wi + 1 < NW) {
      stage(cur ^ 1, wi + 1);       // next window's loads stay in flight
      if constexpr (MODE == 0) asm volatile("s_waitcnt vmcnt(8)" ::: "memory");
      else                     asm volatile("s_waitcnt vmcnt(6)" ::: "memory");
    } else {
      asm volatile("s_waitcnt vmcnt(0)" ::: "memory");
    }
    __builtin_amdgcn_s_barrier();   // current window landed for all waves

    compute(cur, 0);
    compute(cur, 1);

    __builtin_amdgcn_s_barrier();   // reads done before restage
    cur ^= 1;
  }

  // Epilogue. C/D layout: col = lane&15, row = (lane>>4)*4 + i  [m89-verified]
  if constexpr (MODE == 0) {
    if (colbase < 2048) {
      // Q or K block (tiles never cross the 1024 boundary)
      const int selq = colbase >> 10;              // 0=Q 1=K
      unsigned short* dst = selq ? Ko : Qo;
      const float sc = selq ? 1.0f : 0.18033688011112042f;  // 0.125*log2e into Q
#pragma unroll
      for (int n = 0; n < 4; n++) {
        int c = colbase + wc * 64 + n * 16 + lr;
        int hh = (c >> 6) & 15;
        int dd = c & 63;
#pragma unroll
        for (int m = 0; m < WMF; m++) {
          int r0 = rowbase + wr * (WMF * 16) + m * 16 + kf * 4;
#pragma unroll
          for (int i = 0; i < 4; i++) {
            int r = r0 + i;
            int bi = r >> 11;
            int tq = r & 2047;
            dst[((size_t)(bi * NH + hh) * SEQ + tq) * HD + dd] = f2bf(acc[m][n][i] * sc);
          }
        }
      }
    } else {
      // V block: transpose tile in LDS (dead pipeline buffers), store V^T coalesced.
      unsigned short* tr = smem;                   // [128 col][136]
#pragma unroll
      for (int n = 0; n < 4; n++) {
        int ccol = wc * 64 + n * 16 + lr;
#pragma unroll
        for (int m = 0; m < WMF; m++) {
#pragma unroll
          for (int i = 0; i < 4; i++) {
            int rrow = wr * (WMF * 16) + m * 16 + kf * 4 + i;
            tr[ccol * 136 + rrow] = f2bf(acc[m][n][i]);
          }
        }
      }
      __syncthreads();
      const int bi2 = rowbase >> 11;
      const int tq0 = rowbase & 2047;
#pragma unroll
      for (int k2 = 0; k2 < 8; k2++) {
        int u = k2 * 256 + t;                      // 2048 units: [col][seg of 8]
        int cc = u >> 4, seg = u & 15;
        int c = colbase + cc;
        int hh = (c >> 6) & 15, dd = c & 63;
        short8 v8 = *(const short8*)&tr[cc * 136 + seg * 8];
        *(short8*)&Vo[((size_t)(bi2 * NH + hh) * HD + dd) * SEQ + tq0 + seg * 8] = v8;
      }
    }
  } else {
#pragma unroll
    for (int n = 0; n < 4; n++) {
      int c = colbase + wc * 64 + n * 16 + lr;
      float bias = bo[c];
#pragma unroll
      for (int m = 0; m < WMF; m++) {
        int r0 = rowbase + wr * (WMF * 16) + m * 16 + kf * 4;
#pragma unroll
        for (int i = 0; i < 4; i++) {
          out[(size_t)(r0 + i) * 1024 + c] = acc[m][n][i] + bias;
        }
      }
    }
  }
}

// ---------------- flash attention (R6-proven: swapped 32x32, static softmax, paired tiles) ----
// grid: x = b*H (32), y -> qt via CU-pair-balanced remap. 256 thr, 4 waves.
// Wave w owns q rows [qt*128 + w*32, +32). k processed as pairs of 64-subtiles.
__global__ __launch_bounds__(256) void attn_fwd(
    const unsigned short* __restrict__ Q, const unsigned short* __restrict__ K,
    const unsigned short* __restrict__ Vt, unsigned short* __restrict__ ctx) {
  const int bh = blockIdx.x;
  const int y = blockIdx.y;
  const int qt = (y < 8) ? (15 - y) : (y - 8);   // co-resident pairs sum to 36 k-tiles
  const int bi = bh >> 4, hh = bh & 15;
  const int t = threadIdx.x, lane = t & 63, w = t >> 6;
  const int qc = lane & 31, hi = lane >> 5;

  __shared__ __align__(16) unsigned short Ks[2][2][64 * 64];   // [dbuf][sub]
  __shared__ __align__(16) unsigned short Vs[2][2][64 * 64];   // [d][k] swizzled

  const unsigned short* Qb = Q + (size_t)bh * SEQ * HD;
  const unsigned short* Kb = K + (size_t)bh * SEQ * HD;
  const unsigned short* Vb = Vt + (size_t)bh * HD * SEQ;

  const int qrow = qt * 128 + w * 32;
  short8 qv[4];
#pragma unroll
  for (int c = 0; c < 4; c++)
    qv[c] = *(const short8*)&Qb[(size_t)(qrow + qc) * HD + c * 16 + hi * 8];

  f32x16 o0, o1;                    // O^T[d][q]: o0 = d 0..31, o1 = 32..63
#pragma unroll
  for (int i = 0; i < 16; i++) { o0[i] = 0.f; o1[i] = 0.f; }
  float l_acc = 0.f;

  const int ktmax = 2 * qt + (w >> 1);   // last k-tile this wave needs
  const int NP = qt + 1;                 // pairs of 64-k subtiles

  // stage pair p into dbuf buf: two 64-subtiles, proven swizzle
  // (physical 16B chunk f holds logical chunk f ^ ((f>>3)&7); reads XOR back)
  auto stage = [&](int buf, int p) {
#pragma unroll
    for (int sub = 0; sub < 2; sub++) {
      int kt = 2 * p + sub;
#pragma unroll
      for (int i2 = 0; i2 < 2; i2++) {
        int f = i2 * 256 + t;
        int c = f ^ ((f >> 3) & 7);
        async16(Kb + (size_t)kt * 64 * HD + (size_t)c * 8,
                (char*)&Ks[buf][sub][0] + (size_t)f * 16);
        int d = c >> 3, ko = (c & 7) << 3;
        async16(Vb + (size_t)d * SEQ + (size_t)kt * 64 + ko,
                (char*)&Vs[buf][sub][0] + (size_t)f * 16);
      }
    }
  };

  // one 64-k subtile: QK^T -> (mask) -> exp2 -> pack -> PV
  auto tile = [&](const unsigned short* Kt, const unsigned short* Vtile, int kt) {
    f32x16 s0, s1;
#pragma unroll
    for (int i = 0; i < 16; i++) { s0[i] = 0.f; s1[i] = 0.f; }
    __builtin_amdgcn_s_setprio(1);
#pragma unroll
    for (int c = 0; c < 4; c++) {
      int i0 = (qc * 64 + c * 16 + hi * 8) ^ ((qc & 7) << 3);
      s0 = MFMA32(*(const short8*)&Kt[i0], qv[c], s0);
      int r1 = 32 + qc;
      int i1 = (r1 * 64 + c * 16 + hi * 8) ^ ((r1 & 7) << 3);
      s1 = MFMA32(*(const short8*)&Kt[i1], qv[c], s1);
    }
    __builtin_amdgcn_s_setprio(0);

    if (kt == ktmax) {               // causal mask, diagonal tile only
      const int qg = qrow + qc;
#pragma unroll
      for (int reg = 0; reg < 16; reg++) {
        int rloc = (reg & 3) + 8 * (reg >> 2) + 4 * hi;
        int kg = kt * 64 + rloc;
        if (kg > qg) s0[reg] = -1e30f;
        if (kg + 32 > qg) s1[reg] = -1e30f;
      }
    }

    unsigned w0[8], w1[8];
    float psA = 0.f, psB = 0.f;
#pragma unroll
    for (int j = 0; j < 8; j++) {
      float a0 = exp2x(s0[2 * j]), b0 = exp2x(s0[2 * j + 1]);
      float a1 = exp2x(s1[2 * j]), b1 = exp2x(s1[2 * j + 1]);
      psA += a0 + b0;
      psB += a1 + b1;
      w0[j] = cvt_pk(a0, b0);
      w1[j] = cvt_pk(a1, b1);
    }
    l_acc += psA + psB;

    __builtin_amdgcn_s_setprio(1);
#pragma unroll
    for (int h2 = 0; h2 < 2; h2++) {
      unsigned* pw = h2 ? w1 : w0;
#pragma unroll
      for (int cc = 0; cc < 2; cc++) {
        unsigned a0 = pw[cc * 4 + 0], b0 = pw[cc * 4 + 2];
        unsigned a1 = pw[cc * 4 + 1], b1 = pw[cc * 4 + 3];
        pls(a0, b0);                 // (pf0,pf2) both halves in one instr
        pls(a1, b1);                 // (pf1,pf3)
        u32x4 pf; pf[0] = a0; pf[1] = a1; pf[2] = b0; pf[3] = b1;
        short8 pfrag = as_short8(pf);
        int c2 = h2 * 2 + cc;
        int ia = (qc * 64 + c2 * 16 + hi * 8) ^ ((qc & 7) << 3);
        o0 = MFMA32(*(const short8*)&Vtile[ia], pfrag, o0);
        int rb = 32 + qc;
        int ib = (rb * 64 + c2 * 16 + hi * 8) ^ ((rb & 7) << 3);
        o1 = MFMA32(*(const short8*)&Vtile[ib], pfrag, o1);
      }
    }
    __builtin_amdgcn_s_setprio(0);
  };

  stage(0, 0);
  int cur = 0;

  for (int p = 0; p < NP; p++) {
    if (p + 1 < NP) {
      stage(cur ^ 1, p + 1);
      asm volatile("s_waitcnt vmcnt(8)" ::: "memory");  // pair p landed; next in flight
    } else {
      asm volatile("s_waitcnt vmcnt(0)" ::: "memory");
    }
    __builtin_amdgcn_s_barrier();

    if (2 * p <= ktmax)     tile(&Ks[cur][0][0], &Vs[cur][0][0], 2 * p);
    if (2 * p + 1 <= ktmax) tile(&Ks[cur][1][0], &Vs[cur][1][0], 2 * p + 1);

    __builtin_amdgcn_s_barrier();
    cur ^= 1;
  }

  // epilogue: l = in-lane sum + one cross-half swap; O/l -> ctx
  float l = l_acc + __shfl_xor(l_acc, 32);
  float inv = 1.0f / l;
  const size_t rowoff = ((size_t)bi * SEQ + qrow + qc) * DMODEL + hh * HD;
#pragma unroll
  for (int g = 0; g < 4; g++) {
    unsigned pa = cvt_pk(o0[4 * g] * inv, o0[4 * g + 1] * inv);
    unsigned pb = cvt_pk(o0[4 * g + 2] * inv, o0[4 * g + 3] * inv);
    uint2 vv; vv.x = pa; vv.y = pb;
    *(uint2*)&ctx[rowoff + 8 * g + 4 * hi] = vv;
    unsigned pc = cvt_pk(o1[4 * g] * inv, o1[4 * g + 1] * inv);
    unsigned pd = cvt_pk(o1[4 * g + 2] * inv, o1[4 * g + 3] * inv);
    uint2 ww; ww.x = pc; ww.y = pd;
    *(uint2*)&ctx[rowoff + 32 + 8 * g + 4 * hi] = ww;
  }
}

// ---------------- launch ----------------
extern "C" void kernel_launch(void* const* d_in, const int* in_sizes, int n_in,
                              void* d_out, int out_size, void* d_ws, size_t ws_size,
                              hipStream_t stream) {
  const float* x  = (const float*)d_in[0];
  const float* Wq = (const float*)d_in[1];
  const float* Wk = (const float*)d_in[2];
  const float* Wv = (const float*)d_in[3];
  const float* Wo = (const float*)d_in[4];
  const float* bo = (const float*)d_in[5];
  float* out = (float*)d_out;

  unsigned short* xb   = (unsigned short*)d_ws;                 // 4M elems
  unsigned short* Wt   = xb + (size_t)MROWS * DMODEL;           // 3M (Wq^T|Wk^T|Wv^T)
  unsigned short* WoT  = Wt + (size_t)3 * 1024 * 1024;          // 1M
  unsigned short* Qb   = WoT + (size_t)1024 * 1024;             // 4M
  unsigned short* Kb   = Qb + (size_t)MROWS * DMODEL;           // 4M
  unsigned short* Vb   = Kb + (size_t)MROWS * DMODEL;           // 4M  V^T [b,h,d,t]
  unsigned short* ctxb = Vb + (size_t)MROWS * DMODEL;           // 4M

  prep<<<3072, 256, 0, stream>>>(x, Wq, Wk, Wv, Wo, xb, Wt, WoT);

  gemm_bt<0, 4><<<dim3(32, 24), 256, 0, stream>>>(xb, Wt, Qb, Kb, Vb, nullptr, nullptr);
  attn_fwd<<<dim3(32, 16), 256, 0, stream>>>(Qb, Kb, Vb, ctxb);
  gemm_bt<1, 2><<<dim3(64, 8), 256, 0, stream>>>(ctxb, WoT, nullptr, nullptr, nullptr, out, bo);
}